// Round 5
// baseline (162.589 us; speedup 1.0000x reference)
//
#include <hip/hip_runtime.h>
#include <stdint.h>

// QLinear: out = dequant((quant(x) @ qkernel + qbias) mod 2^16)
// N=8192, DIN=2048, DOUT=2048
//
// 2 kernels:
//   kp: blocks [0,8192): quantize x -> xq (u8 ^0x80), 128*rowsum -> rs128
//       blocks [8192,9216): transpose qkernel -> qkT (^0x80), qbias -> qb32
//   kg: 256x256 i8 MFMA GEMM, 4 phases/K-tile in m201 order:
//       ds_read+stage BEFORE barrier -> barrier hides LDS latency ->
//       lgkmcnt(0) -> MFMA cluster; counted vmcnt(4) twice per tile.
//
// ws layout (~20.04 MiB):
//   xq    [8192][2048] u8   @ 0
//   qkT   [2048][2048] u8   @ 16 MiB   (n-major, ^0x80)
//   rs128 [8192] i32        @ 20 MiB
//   qb32  [2048] i32        @ 20 MiB + 32 KiB

#define NROWS 8192
#define DIN   2048
#define DOUT  2048

typedef int v4i __attribute__((ext_vector_type(4)));

__device__ inline void gload16(const uint8_t* g, uint8_t* l) {
  __builtin_amdgcn_global_load_lds(
      (__attribute__((address_space(1))) void*)(g),
      (__attribute__((address_space(3))) void*)(l), 16, 0, 0);
}

__device__ inline void wgbar() {
  __builtin_amdgcn_sched_barrier(0);
  __builtin_amdgcn_s_barrier();
  __builtin_amdgcn_sched_barrier(0);
}

// ---------------- prep: quantize+rowsum | transpose+bias ----------------
__device__ inline uint32_t q4(float4 v, float inv, float z, int& sum) {
  uint32_t w = 0;
  float e[4] = {v.x, v.y, v.z, v.w};
#pragma unroll
  for (int i = 0; i < 4; ++i) {
    float tq = rintf(e[i] * inv) + z;      // == rintf(x/s)+zp for s=0.5 (exact)
    tq = fminf(fmaxf(tq, 0.0f), 255.0f);   // clip
    uint32_t q = (uint32_t)tq;             // trunc == astype(uint8) after clip
    sum += (int)q;
    w |= ((q ^ 0x80u) & 0xFFu) << (8 * i); // signed bits for MFMA
  }
  return w;
}

__global__ __launch_bounds__(256) void kp(const float* __restrict__ x,
                                          const float* __restrict__ sp,
                                          const float* __restrict__ zpp,
                                          const void* __restrict__ qk,
                                          const void* __restrict__ qbias,
                                          uint8_t* __restrict__ xq,
                                          int* __restrict__ rs128,
                                          uint8_t* __restrict__ qkT,
                                          int* __restrict__ qb32) {
  const int t = threadIdx.x;
  if (blockIdx.x < NROWS) {
    // ---- quantize one row ----
    const int row = blockIdx.x;
    const float s = sp[0], z = zpp[0];
    const float inv = 1.0f / s;            // s=0.5 -> 2.0 exact
    const float4* xr = (const float4*)(x + (size_t)row * DIN);
    float4 a = xr[t];
    float4 b = xr[t + 256];
    int sum = 0;
    uint32_t w0 = q4(a, inv, z, sum);
    uint32_t w1 = q4(b, inv, z, sum);
    uint32_t* xw = (uint32_t*)(xq + (size_t)row * DIN);
    xw[t] = w0;
    xw[t + 256] = w1;
#pragma unroll
    for (int o = 32; o > 0; o >>= 1) sum += __shfl_down(sum, o);
    __shared__ int ws4[4];
    if ((t & 63) == 0) ws4[t >> 6] = sum;
    __syncthreads();
    if (t == 0) rs128[row] = 128 * (ws4[0] + ws4[1] + ws4[2] + ws4[3]);
    return;
  }
  // ---- transpose one 64x64 tile of qkernel ----
  __shared__ uint8_t tile[64][68];
  __shared__ int sflag;
  if (t == 0) sflag = 0;
  __syncthreads();
  {  // dtype self-detect on fixed first 1 KiB (deterministic, L2-hit)
    const int* q32 = (const int*)qk;
    int bad = 0;
#pragma unroll
    for (int i = 0; i < 4; ++i) bad |= ((unsigned)q32[t + 256 * i] > 255u);
    if (bad) sflag = 1;  // benign race, all writers store 1
  }
  __syncthreads();
  const int u8mode = sflag;

  const int j = blockIdx.x - NROWS;
  const int n0 = (j & 31) * 64;
  const int k0 = (j >> 5) * 64;
  const int tx = t & 15;
  const int ty = t >> 4;
  if (u8mode) {
    const uint8_t* q8 = (const uint8_t*)qk;
#pragma unroll
    for (int jj = 0; jj < 4; ++jj) {
      int r = jj * 16 + ty;
      uint32_t w = *(const uint32_t*)(q8 + (size_t)(k0 + r) * DOUT + n0 + tx * 4);
      tile[r][tx * 4 + 0] = (uint8_t)(w & 255u);
      tile[r][tx * 4 + 1] = (uint8_t)((w >> 8) & 255u);
      tile[r][tx * 4 + 2] = (uint8_t)((w >> 16) & 255u);
      tile[r][tx * 4 + 3] = (uint8_t)((w >> 24) & 255u);
    }
  } else {
    const int* q32 = (const int*)qk;
#pragma unroll
    for (int jj = 0; jj < 4; ++jj) {
      int r = jj * 16 + ty;
      int4 w = *(const int4*)(q32 + (size_t)(k0 + r) * DOUT + n0 + tx * 4);
      tile[r][tx * 4 + 0] = (uint8_t)w.x;
      tile[r][tx * 4 + 1] = (uint8_t)w.y;
      tile[r][tx * 4 + 2] = (uint8_t)w.z;
      tile[r][tx * 4 + 3] = (uint8_t)w.w;
    }
  }
  __syncthreads();
#pragma unroll
  for (int jj = 0; jj < 4; ++jj) {
    int r = jj * 16 + ty;  // n within tile
    uint32_t b0 = tile[tx * 4 + 0][r];
    uint32_t b1 = tile[tx * 4 + 1][r];
    uint32_t b2 = tile[tx * 4 + 2][r];
    uint32_t b3 = tile[tx * 4 + 3][r];
    *(uint32_t*)(qkT + (size_t)(n0 + r) * DIN + k0 + tx * 4) =
        (b0 ^ 0x80u) | ((b1 ^ 0x80u) << 8) | ((b2 ^ 0x80u) << 16) | ((b3 ^ 0x80u) << 24);
  }
  if (k0 == 0 && t < 64) {  // qbias -> i32, once per column
    int n = n0 + t;
    qb32[n] = u8mode ? (int)((const uint16_t*)qbias)[n] : ((const int*)qbias)[n];
  }
}

// ---------------- i8 MFMA GEMM, 256x256 tile, BK=128, m201 phase order ----
// LDS: A [buf][ks][256 rows][64B] @ buf*32768 + ks*16384; B same @ +65536.
// 16B-chunk swizzle c ^= (row>>1)&3 (measured 0-conflict r2/r4); applied on
// pre-swizzled global source AND ds_read (involution).
// Phase = { ds_read frags ; stage next-tile unit ; barrier ; lgkmcnt(0) ;
//           MFMA cluster ; [vmcnt(4) at phases 1,3] ; barrier }
// -> the barrier-arrival slack hides ds_read latency (T3); vmcnt never 0 (T4).
__global__ __launch_bounds__(512, 2) void kg(const uint8_t* __restrict__ A,
                                             const uint8_t* __restrict__ B,
                                             const int* __restrict__ rs128,
                                             const int* __restrict__ qb32,
                                             const float* __restrict__ sp,
                                             const float* __restrict__ zpp,
                                             float* __restrict__ out) {
  __shared__ __align__(16) uint8_t lds[131072];
  const int t = threadIdx.x;
  const int l = t & 63, wid = t >> 6;
  const int wr = wid >> 2, wc = wid & 3;      // 2M x 4N waves, each 128x64 out
  const int rl = l & 15, kgp = l >> 4;

  // XCD-aware swizzle (256 blocks, 8 XCDs -> bijective)
  const int bid = blockIdx.x;
  const int swz = (bid & 7) * 32 + (bid >> 3);
  const int m0 = (swz >> 3) * 256;
  const int n0 = (swz & 7) * 256;

  // staging: per unit (matrix,ks) each thread does 2x gload16
  const int srow = t >> 2;                    // 0..127
  const int sc = (t & 3) ^ ((srow >> 1) & 3); // source chunk (pre-swizzled)
  const uint8_t* gA = A + (size_t)(m0 + srow) * DIN + sc * 16;
  const uint8_t* gA2 = gA + (size_t)128 * DIN;
  const uint8_t* gB = B + (size_t)(n0 + srow) * DIN + sc * 16;
  const uint8_t* gB2 = gB + (size_t)128 * DIN;
  const int sdst = t * 16;

#define STAGE_A(BUF, KS, KB) do {                                   \
    uint8_t* d_ = lds + (BUF) * 32768 + (KS) * 16384 + sdst;        \
    gload16(gA + (KB) + (KS) * 64, d_);                             \
    gload16(gA2 + (KB) + (KS) * 64, d_ + 8192);                     \
  } while (0)
#define STAGE_B(BUF, KS, KB) do {                                   \
    uint8_t* d_ = lds + 65536 + (BUF) * 32768 + (KS) * 16384 + sdst;\
    gload16(gB + (KB) + (KS) * 64, d_);                             \
    gload16(gB2 + (KB) + (KS) * 64, d_ + 8192);                     \
  } while (0)

  const int swl = (rl >> 1) & 3;              // read-side swizzle (row bits 1:2)
  const int aoff0 = (wr * 128 + rl) * 64 + ((kgp ^ swl) << 4);
  const int boff0 = 65536 + (wc * 64 + rl) * 64 + ((kgp ^ swl) << 4);

  v4i acc[8][4];
#pragma unroll
  for (int i = 0; i < 8; ++i)
#pragma unroll
    for (int j = 0; j < 4; ++j) acc[i][j] = (v4i){0, 0, 0, 0};
  v4i csum[4];
#pragma unroll
  for (int j = 0; j < 4; ++j) csum[j] = (v4i){0, 0, 0, 0};
  const v4i ones = (v4i){0x01010101, 0x01010101, 0x01010101, 0x01010101};
  v4i af[4], bf[4];

#define LD_A(MH, KH) do {                                            \
    const uint8_t* ap_ = lds + cur * 32768 + (KH) * 16384 + aoff0 + (MH) * 4096; \
    _Pragma("unroll")                                                \
    for (int q = 0; q < 4; ++q) af[q] = *(const v4i*)(ap_ + q * 1024);\
  } while (0)
#define LD_B(KH) do {                                                \
    const uint8_t* bp_ = lds + cur * 32768 + (KH) * 16384 + boff0;   \
    _Pragma("unroll")                                                \
    for (int nj = 0; nj < 4; ++nj) bf[nj] = *(const v4i*)(bp_ + nj * 1024); \
  } while (0)
// Wait for this phase's ds_reads (issued pre-barrier), pin MFMA below it.
#define LGKM0() do {                                                 \
    asm volatile("s_waitcnt lgkmcnt(0)" ::: "memory");               \
    __builtin_amdgcn_sched_barrier(0);                               \
  } while (0)
#define CLUSTER(MH, CS) do {                                         \
    __builtin_amdgcn_s_setprio(1);                                   \
    _Pragma("unroll")                                                \
    for (int q = 0; q < 4; ++q)                                      \
      _Pragma("unroll")                                              \
      for (int nj = 0; nj < 4; ++nj)                                 \
        acc[(MH) * 4 + q][nj] = __builtin_amdgcn_mfma_i32_16x16x64_i8(\
            af[q], bf[nj], acc[(MH) * 4 + q][nj], 0, 0, 0);          \
    if (CS) {                                                        \
      _Pragma("unroll")                                              \
      for (int nj = 0; nj < 4; ++nj)                                 \
        csum[nj] = __builtin_amdgcn_mfma_i32_16x16x64_i8(            \
            ones, bf[nj], csum[nj], 0, 0, 0);                        \
    }                                                                \
    __builtin_amdgcn_s_setprio(0);                                   \
  } while (0)

  // prologue: stage tile 0 into buf 0 (issue order = wait order: A0,B0,A1,B1)
  STAGE_A(0, 0, 0);
  STAGE_B(0, 0, 0);
  STAGE_A(0, 1, 0);
  STAGE_B(0, 1, 0);
  asm volatile("s_waitcnt vmcnt(4)" ::: "memory");  // A0,B0 of tile 0 landed
  wgbar();

  int cur = 0;
  for (int tt = 0; tt < 16; ++tt) {
    const int nb = cur ^ 1;
    const int kn = ((tt + 1) & 15) * 128;  // wraps at tail (harmless reload)

    // p0: cluster (kh0, mh0) + csum(kh0)
    LD_B(0);
    LD_A(0, 0);
    STAGE_A(nb, 0, kn);
    wgbar();
    LGKM0();
    CLUSTER(0, 1);
    wgbar();

    // p1: cluster (kh0, mh1); then drain tile tt's ks1 loads (A1,B1)
    LD_A(1, 0);
    STAGE_B(nb, 0, kn);
    wgbar();
    LGKM0();
    CLUSTER(1, 0);
    asm volatile("s_waitcnt vmcnt(4)" ::: "memory");
    wgbar();

    // p2: cluster (kh1, mh0) + csum(kh1)
    LD_B(1);
    LD_A(0, 1);
    STAGE_A(nb, 1, kn);
    wgbar();
    LGKM0();
    CLUSTER(0, 1);
    wgbar();

    // p3: cluster (kh1, mh1); then drain next tile's ks0 loads (A0',B0')
    LD_A(1, 1);
    STAGE_B(nb, 1, kn);
    wgbar();
    LGKM0();
    CLUSTER(1, 0);
    asm volatile("s_waitcnt vmcnt(4)" ::: "memory");
    wgbar();

    cur = nb;
  }

  // Epilogue: Σab ≡ D + 128*rowsum_u(a) + 128*Σ(b-128)  (mod 2^16)
  //   (cross terms 128^2*K = 2^25 ≡ 0). csum lane value = Σ_k b'[k][col(rl)].
  const float s = sp[0], z = zpp[0];
  int cc[4];
#pragma unroll
  for (int nj = 0; nj < 4; ++nj) cc[nj] = (csum[nj][0] << 7) + qb32[n0 + wc * 64 + nj * 16 + rl];
#pragma unroll
  for (int mi = 0; mi < 8; ++mi) {
#pragma unroll
    for (int r = 0; r < 4; ++r) {
      int row = m0 + wr * 128 + mi * 16 + kgp * 4 + r;  // C/D: col=l&15, row=(l>>4)*4+reg
      int rs = rs128[row];
#pragma unroll
      for (int nj = 0; nj < 4; ++nj) {
        int col = n0 + wc * 64 + nj * 16 + rl;
        uint32_t v = (uint32_t)(acc[mi][nj][r] + rs + cc[nj]) & 0xFFFFu;
        out[(size_t)row * DOUT + col] = ((float)v - z) * s;
      }
    }
  }
#undef STAGE_A
#undef STAGE_B
#undef LD_A
#undef LD_B
#undef LGKM0
#undef CLUSTER
}

extern "C" void kernel_launch(void* const* d_in, const int* in_sizes, int n_in,
                              void* d_out, int out_size, void* d_ws, size_t ws_size,
                              hipStream_t stream) {
  const float* x   = (const float*)d_in[0];
  const float* sp  = (const float*)d_in[1];
  const float* zpp = (const float*)d_in[2];
  const void*  qk  = d_in[3];
  const void*  qb  = d_in[4];
  float* out = (float*)d_out;

  uint8_t* ws = (uint8_t*)d_ws;
  uint8_t* xq  = ws;
  uint8_t* qkT = ws + (16u << 20);
  int* rs128 = (int*)(ws + (20u << 20));
  int* qb32  = (int*)(ws + (20u << 20) + (32u << 10));

  kp<<<NROWS + (DIN / 64) * (DOUT / 64), 256, 0, stream>>>(
      x, sp, zpp, qk, qb, xq, rs128, qkT, qb32);
  kg<<<dim3(256), 512, 0, stream>>>(xq, qkT, rs128, qb32, sp, zpp, out);
}